// Round 2
// baseline (133.815 us; speedup 1.0000x reference)
//
#include <hip/hip_runtime.h>
#include <hip/hip_bf16.h>

// Gauss linking integral between kinematic-chain segment pairs.
// motion1, motion2: (B=32, F=1024, J=22, 3) fp32.
// 16 segments per motion (5 paths). gli[b,f,pp] = sum of gauss integrals.
// out[b,f] = max_pp |gli[b,f+1,pp] - gli[b,f,pp]|, shape (32, 1023).

#define NFRAMES 1024
#define NBATCH  32

__constant__ int c_seg_a[16] = {2,5,8,  1,4,7,  3,6,9,12,  14,17,19,  13,16,18};
__constant__ int c_seg_b[16] = {5,8,11, 4,7,10, 6,9,12,15, 17,19,21,  16,18,20};
__constant__ int c_seg_p[16] = {0,0,0,  1,1,1,  2,2,2,2,   3,3,3,     4,4,4};

struct V3 { float x, y, z; };

__device__ __forceinline__ V3 vsub(V3 a, V3 b) { return {a.x-b.x, a.y-b.y, a.z-b.z}; }
__device__ __forceinline__ V3 vcross(V3 a, V3 b) {
    return {fmaf(a.y, b.z, -a.z*b.y), fmaf(a.z, b.x, -a.x*b.z), fmaf(a.x, b.y, -a.y*b.x)};
}
__device__ __forceinline__ float vdot(V3 a, V3 b) {
    return fmaf(a.x, b.x, fmaf(a.y, b.y, a.z*b.z));
}

// asin via Abramowitz-Stegun 4.4.46 (7-term): |err| <= 2e-8, branchless.
__device__ __forceinline__ float fast_asin(float x) {
    float ax = fabsf(x);
    float p = fmaf(ax, -0.0012624911f, 0.0066700901f);
    p = fmaf(ax, p, -0.0170881256f);
    p = fmaf(ax, p,  0.0308918810f);
    p = fmaf(ax, p, -0.0501743046f);
    p = fmaf(ax, p,  0.0889789874f);
    p = fmaf(ax, p, -0.2145988016f);
    p = fmaf(ax, p,  1.5707963050f);
    float r = fmaf(-__builtin_amdgcn_sqrtf(1.0f - ax), p, 1.57079632679f);
    return copysignf(r, x);
}

// One block = one (b,f) cell. 256 threads = 16x16 segment pairs.
__global__ __launch_bounds__(256)
void gli_kernel(const float* __restrict__ m1, const float* __restrict__ m2,
                float* __restrict__ gli)
{
    __shared__ float j1[66];   // 22 joints x 3
    __shared__ float j2[66];
    __shared__ float sums[25];

    const int bf = blockIdx.x;
    const int t  = threadIdx.x;
    const size_t base = (size_t)bf * 66;

    if (t < 66)       j1[t]      = m1[base + t];
    else if (t < 132) j2[t - 66] = m2[base + (t - 66)];
    if (t < 25) sums[t] = 0.0f;
    __syncthreads();

    const int i1 = t >> 4;    // motion1 segment index
    const int i2 = t & 15;    // motion2 segment index

    const int a1 = c_seg_a[i1] * 3, b1 = c_seg_b[i1] * 3;
    const int a2 = c_seg_a[i2] * 3, b2 = c_seg_b[i2] * 3;

    V3 S1{j1[a1], j1[a1+1], j1[a1+2]};
    V3 E1{j1[b1], j1[b1+1], j1[b1+2]};
    V3 S2{j2[a2], j2[a2+1], j2[a2+2]};
    V3 E2{j2[b2], j2[b2+1], j2[b2+2]};

    V3 r13 = vsub(S2, S1);
    V3 r14 = vsub(E2, S1);
    V3 r23 = vsub(S2, E1);
    V3 r24 = vsub(E2, E1);
    V3 r12 = vsub(E1, S1);
    V3 r34 = vsub(E2, S2);

    // Unnormalized face normals; normalize the dots instead of the vectors.
    V3 c0 = vcross(r13, r14);
    V3 c1 = vcross(r14, r24);
    V3 c2 = vcross(r24, r23);
    V3 c3 = vcross(r23, r13);

    float n0 = vdot(c0, c0), n1 = vdot(c1, c1), n2 = vdot(c2, c2), n3 = vdot(c3, c3);

    float q01 = n0 * n1, q12 = n1 * n2, q23 = n2 * n3, q30 = n3 * n0;
    // ref: zero-norm face -> nf = 0 -> dot contribution 0.
    float i01 = (q01 > 0.0f) ? __builtin_amdgcn_rsqf(q01) : 0.0f;
    float i12 = (q12 > 0.0f) ? __builtin_amdgcn_rsqf(q12) : 0.0f;
    float i23 = (q23 > 0.0f) ? __builtin_amdgcn_rsqf(q23) : 0.0f;
    float i30 = (q30 > 0.0f) ? __builtin_amdgcn_rsqf(q30) : 0.0f;

    const float lo = -1.0f + 1e-7f, hi = 1.0f - 1e-7f;
    float d0 = fminf(fmaxf(vdot(c0, c1) * i01, lo), hi);
    float d1 = fminf(fmaxf(vdot(c1, c2) * i12, lo), hi);
    float d2 = fminf(fmaxf(vdot(c2, c3) * i23, lo), hi);
    float d3 = fminf(fmaxf(vdot(c3, c0) * i30, lo), hi);

    float g = fast_asin(d0) + fast_asin(d1) + fast_asin(d2) + fast_asin(d3);

    float sgn = vdot(vcross(r34, r12), r13);
    g = (sgn <= 0.0f) ? -g : g;
    g *= 0.07957747154594767f;  // 1/(4*pi)

    atomicAdd(&sums[c_seg_p[i1] * 5 + c_seg_p[i2]], g);
    __syncthreads();

    if (t < 25) gli[(size_t)bf * 25 + t] = sums[t];
}

// out[b,f] = max_p |gli[b,f+1,p] - gli[b,f,p]|
__global__ __launch_bounds__(256)
void vel_kernel(const float* __restrict__ gli, float* __restrict__ out)
{
    const int f = blockIdx.x * blockDim.x + threadIdx.x;
    const int b = blockIdx.y;
    if (f >= NFRAMES - 1) return;

    const float* p0 = gli + ((size_t)b * NFRAMES + f) * 25;
    float m = 0.0f;
#pragma unroll
    for (int p = 0; p < 25; ++p)
        m = fmaxf(m, fabsf(p0[p + 25] - p0[p]));
    out[(size_t)b * (NFRAMES - 1) + f] = m;
}

extern "C" void kernel_launch(void* const* d_in, const int* in_sizes, int n_in,
                              void* d_out, int out_size, void* d_ws, size_t ws_size,
                              hipStream_t stream)
{
    const float* m1 = (const float*)d_in[0];
    const float* m2 = (const float*)d_in[1];
    float* out = (float*)d_out;
    float* gli = (float*)d_ws;   // 32*1024*25*4 = 3.3 MB

    hipLaunchKernelGGL(gli_kernel, dim3(NBATCH * NFRAMES), dim3(256), 0, stream,
                       m1, m2, gli);
    hipLaunchKernelGGL(vel_kernel, dim3((NFRAMES - 1 + 255) / 256, NBATCH), dim3(256),
                       0, stream, gli, out);
}

// Round 3
// 133.628 us; speedup vs baseline: 1.0014x; 1.0014x over previous
//
#include <hip/hip_runtime.h>
#include <hip/hip_bf16.h>

// Gauss linking integral between kinematic-chain segment pairs, fused.
// motion1, motion2: (B=32, F=1024, J=22, 3) fp32.
// 16 segments per motion (5 paths). gli[b,f,pp] = sum of gauss integrals over
// segment pairs in path-pair pp. out[b,f] = max_pp |gli[b,f+1,pp]-gli[b,f,pp]|.
// One block = (b, chunk of 16 output frames): computes 17 frames' gli in LDS,
// emits 16 vel outputs. Whole grid (64x32=2048 blocks) resident at once.

#define NF 1024
#define NB 32
#define FCHUNK 16           // vel outputs per block; computes FCHUNK+1 frames

__constant__ int c_seg_a[16] = {2,5,8,  1,4,7,  3,6,9,12,  14,17,19,  13,16,18};
__constant__ int c_seg_b[16] = {5,8,11, 4,7,10, 6,9,12,15, 17,19,21,  16,18,20};
__constant__ int c_seg_p[16] = {0,0,0,  1,1,1,  2,2,2,2,   3,3,3,     4,4,4};

struct V3 { float x, y, z; };

__device__ __forceinline__ V3 vsub(V3 a, V3 b) { return {a.x-b.x, a.y-b.y, a.z-b.z}; }
__device__ __forceinline__ V3 vcross(V3 a, V3 b) {
    return {fmaf(a.y, b.z, -a.z*b.y), fmaf(a.z, b.x, -a.x*b.z), fmaf(a.x, b.y, -a.y*b.x)};
}
__device__ __forceinline__ float vdot(V3 a, V3 b) {
    return fmaf(a.x, b.x, fmaf(a.y, b.y, a.z*b.z));
}

// asin via Abramowitz-Stegun 4.4.46 (7-term): |err| <= 2e-8, branchless.
__device__ __forceinline__ float fast_asin(float x) {
    float ax = fabsf(x);
    float p = fmaf(ax, -0.0012624911f, 0.0066700901f);
    p = fmaf(ax, p, -0.0170881256f);
    p = fmaf(ax, p,  0.0308918810f);
    p = fmaf(ax, p, -0.0501743046f);
    p = fmaf(ax, p,  0.0889789874f);
    p = fmaf(ax, p, -0.2145988016f);
    p = fmaf(ax, p,  1.5707963050f);
    float r = fmaf(-__builtin_amdgcn_sqrtf(1.0f - ax), p, 1.57079632679f);
    return copysignf(r, x);
}

__global__ __launch_bounds__(256)
void fused_gli_vel(const float* __restrict__ m1, const float* __restrict__ m2,
                   float* __restrict__ out)
{
    __shared__ float j1[(FCHUNK + 1) * 66];   // 17 frames x 22 joints x 3
    __shared__ float j2[(FCHUNK + 1) * 66];
    __shared__ float sums[(FCHUNK + 1) * 25];

    const int f0 = blockIdx.x * FCHUNK;
    const int b  = blockIdx.y;
    const int t  = threadIdx.x;

    for (int i = t; i < (FCHUNK + 1) * 25; i += 256) sums[i] = 0.0f;

    // Stage 17 frames of both motions (coalesced; last chunk clamps frame idx).
    const size_t mbase = (size_t)b * NF * 66;
    for (int i = t; i < (FCHUNK + 1) * 66; i += 256) {
        int fk  = i / 66;
        int off = i - fk * 66;
        int fidx = f0 + fk; if (fidx > NF - 1) fidx = NF - 1;
        size_t ga = mbase + (size_t)fidx * 66 + off;
        j1[i] = m1[ga];
        j2[i] = m2[ga];
    }
    __syncthreads();

    const int i1 = t >> 4;    // motion1 segment index
    const int i2 = t & 15;    // motion2 segment index
    const int a1 = c_seg_a[i1] * 3, b1 = c_seg_b[i1] * 3;
    const int a2 = c_seg_a[i2] * 3, b2 = c_seg_b[i2] * 3;
    const int bin = c_seg_p[i1] * 5 + c_seg_p[i2];

    for (int k = 0; k <= FCHUNK; ++k) {
        const float* J1 = j1 + k * 66;
        const float* J2 = j2 + k * 66;

        V3 S1{J1[a1], J1[a1+1], J1[a1+2]};
        V3 E1{J1[b1], J1[b1+1], J1[b1+2]};
        V3 S2{J2[a2], J2[a2+1], J2[a2+2]};
        V3 E2{J2[b2], J2[b2+1], J2[b2+2]};

        V3 r13 = vsub(S2, S1);
        V3 r14 = vsub(E2, S1);
        V3 r23 = vsub(S2, E1);
        V3 r24 = vsub(E2, E1);
        V3 r12 = vsub(E1, S1);
        V3 r34 = vsub(E2, S2);

        // Unnormalized face normals; normalize the dots instead of the vectors.
        V3 c0 = vcross(r13, r14);
        V3 c1 = vcross(r14, r24);
        V3 c2 = vcross(r24, r23);
        V3 c3 = vcross(r23, r13);

        float n0 = vdot(c0, c0), n1 = vdot(c1, c1);
        float n2 = vdot(c2, c2), n3 = vdot(c3, c3);

        float q01 = n0 * n1, q12 = n1 * n2, q23 = n2 * n3, q30 = n3 * n0;
        // ref: zero-norm face -> nf = 0 -> dot contribution 0.
        float i01 = (q01 > 0.0f) ? __builtin_amdgcn_rsqf(q01) : 0.0f;
        float i12 = (q12 > 0.0f) ? __builtin_amdgcn_rsqf(q12) : 0.0f;
        float i23 = (q23 > 0.0f) ? __builtin_amdgcn_rsqf(q23) : 0.0f;
        float i30 = (q30 > 0.0f) ? __builtin_amdgcn_rsqf(q30) : 0.0f;

        const float lo = -1.0f + 1e-7f, hi = 1.0f - 1e-7f;
        float d0 = fminf(fmaxf(vdot(c0, c1) * i01, lo), hi);
        float d1 = fminf(fmaxf(vdot(c1, c2) * i12, lo), hi);
        float d2 = fminf(fmaxf(vdot(c2, c3) * i23, lo), hi);
        float d3 = fminf(fmaxf(vdot(c3, c0) * i30, lo), hi);

        float g = fast_asin(d0) + fast_asin(d1) + fast_asin(d2) + fast_asin(d3);

        float sgn = vdot(vcross(r34, r12), r13);
        g = (sgn <= 0.0f) ? -g : g;
        g *= 0.07957747154594767f;  // 1/(4*pi)

        atomicAdd(&sums[k * 25 + bin], g);
    }
    __syncthreads();

    // vel: out[b,f] = max_p |sums[k+1][p] - sums[k][p]|
    if (t < FCHUNK) {
        int f = f0 + t;
        if (f < NF - 1) {
            const float* s0 = sums + t * 25;
            float m = 0.0f;
#pragma unroll
            for (int p = 0; p < 25; ++p)
                m = fmaxf(m, fabsf(s0[p + 25] - s0[p]));
            out[(size_t)b * (NF - 1) + f] = m;
        }
    }
}

extern "C" void kernel_launch(void* const* d_in, const int* in_sizes, int n_in,
                              void* d_out, int out_size, void* d_ws, size_t ws_size,
                              hipStream_t stream)
{
    const float* m1 = (const float*)d_in[0];
    const float* m2 = (const float*)d_in[1];
    float* out = (float*)d_out;

    hipLaunchKernelGGL(fused_gli_vel, dim3(NF / FCHUNK, NB), dim3(256), 0, stream,
                       m1, m2, out);
}

// Round 4
// 100.110 us; speedup vs baseline: 1.3367x; 1.3348x over previous
//
#include <hip/hip_runtime.h>
#include <hip/hip_bf16.h>

// Gauss linking integral between kinematic-chain segment pairs.
// motion1, motion2: (B=32, F=1024, J=22, 3) fp32.
// Restructure vs R2: one thread owns (frame, i1-segment) -> p1 fixed ->
// accumulate the 16 i2-pairs into 5 REGISTERS (no LDS atomics at all).
// Non-atomic LDS transpose + grouped sum emits gli; tiny vel kernel follows.

#define NF 1024
#define NB 32
#define FPB 16              // frames per block (256 threads = 16 frames x 16 i1)

__constant__ int c_seg_a[16] = {2,5,8,  1,4,7,  3,6,9,12,  14,17,19,  13,16,18};
__constant__ int c_seg_b[16] = {5,8,11, 4,7,10, 6,9,12,15, 17,19,21,  16,18,20};
__constant__ int c_seg_p[16] = {0,0,0,  1,1,1,  2,2,2,2,   3,3,3,     4,4,4};
__constant__ int c_grp_s[5]  = {0, 3, 6, 10, 13};   // first i1 of each path
__constant__ int c_grp_e[5]  = {3, 6, 10, 13, 16};  // one-past-last i1

struct V3 { float x, y, z; };

__device__ __forceinline__ V3 vsub(V3 a, V3 b) { return {a.x-b.x, a.y-b.y, a.z-b.z}; }
__device__ __forceinline__ V3 vcross(V3 a, V3 b) {
    return {fmaf(a.y, b.z, -a.z*b.y), fmaf(a.z, b.x, -a.x*b.z), fmaf(a.x, b.y, -a.y*b.x)};
}
__device__ __forceinline__ float vdot(V3 a, V3 b) {
    return fmaf(a.x, b.x, fmaf(a.y, b.y, a.z*b.z));
}

// asin via Abramowitz-Stegun 4.4.46 (7-term): |err| <= 2e-8, branchless.
__device__ __forceinline__ float fast_asin(float x) {
    float ax = fabsf(x);
    float p = fmaf(ax, -0.0012624911f, 0.0066700901f);
    p = fmaf(ax, p, -0.0170881256f);
    p = fmaf(ax, p,  0.0308918810f);
    p = fmaf(ax, p, -0.0501743046f);
    p = fmaf(ax, p,  0.0889789874f);
    p = fmaf(ax, p, -0.2145988016f);
    p = fmaf(ax, p,  1.5707963050f);
    float r = fmaf(-__builtin_amdgcn_sqrtf(1.0f - ax), p, 1.57079632679f);
    return copysignf(r, x);
}

// smem layout: j1[FPB*66] | j2[FPB*66]; red[FPB][16][5] aliases the j1 region
// after a barrier (4224 floats available, red needs 1280).
__global__ __launch_bounds__(256)
void gli_kernel(const float* __restrict__ m1, const float* __restrict__ m2,
                float* __restrict__ gli)
{
    __shared__ float smem[FPB * 66 * 2];
    float* j1 = smem;
    float* j2 = smem + FPB * 66;

    const int f0 = blockIdx.x * FPB;
    const int b  = blockIdx.y;
    const int t  = threadIdx.x;

    // Stage FPB frames of both motions (coalesced).
    const size_t mbase = ((size_t)b * NF + f0) * 66;
    for (int i = t; i < FPB * 66; i += 256) {
        j1[i] = m1[mbase + i];
        j2[i] = m2[mbase + i];
    }
    __syncthreads();

    const int k  = t >> 4;    // frame within block
    const int i1 = t & 15;    // motion1 segment (fixed per thread -> p1 fixed)
    const float* J1 = j1 + k * 66;
    const float* J2 = j2 + k * 66;

    const int a1 = c_seg_a[i1] * 3, b1 = c_seg_b[i1] * 3;
    V3 S1{J1[a1], J1[a1+1], J1[a1+2]};
    V3 E1{J1[b1], J1[b1+1], J1[b1+2]};
    V3 r12 = vsub(E1, S1);

    float acc[5] = {0.0f, 0.0f, 0.0f, 0.0f, 0.0f};

#pragma unroll
    for (int i2 = 0; i2 < 16; ++i2) {
        const int a2 = c_seg_a[i2] * 3, b2 = c_seg_b[i2] * 3;
        V3 S2{J2[a2], J2[a2+1], J2[a2+2]};   // 16-lane broadcast reads
        V3 E2{J2[b2], J2[b2+1], J2[b2+2]};

        V3 r13 = vsub(S2, S1);
        V3 r14 = vsub(E2, S1);
        V3 r23 = vsub(S2, E1);
        V3 r24 = vsub(E2, E1);
        V3 r34 = vsub(E2, S2);

        V3 c0 = vcross(r13, r14);
        V3 c1 = vcross(r14, r24);
        V3 c2 = vcross(r24, r23);
        V3 c3 = vcross(r23, r13);

        float n0 = vdot(c0, c0), n1 = vdot(c1, c1);
        float n2 = vdot(c2, c2), n3 = vdot(c3, c3);

        float q01 = n0 * n1, q12 = n1 * n2, q23 = n2 * n3, q30 = n3 * n0;
        float i01 = (q01 > 0.0f) ? __builtin_amdgcn_rsqf(q01) : 0.0f;
        float i12 = (q12 > 0.0f) ? __builtin_amdgcn_rsqf(q12) : 0.0f;
        float i23 = (q23 > 0.0f) ? __builtin_amdgcn_rsqf(q23) : 0.0f;
        float i30 = (q30 > 0.0f) ? __builtin_amdgcn_rsqf(q30) : 0.0f;

        const float lo = -1.0f + 1e-7f, hi = 1.0f - 1e-7f;
        float d0 = fminf(fmaxf(vdot(c0, c1) * i01, lo), hi);
        float d1 = fminf(fmaxf(vdot(c1, c2) * i12, lo), hi);
        float d2 = fminf(fmaxf(vdot(c2, c3) * i23, lo), hi);
        float d3 = fminf(fmaxf(vdot(c3, c0) * i30, lo), hi);

        float g = fast_asin(d0) + fast_asin(d1) + fast_asin(d2) + fast_asin(d3);

        float sgn = vdot(vcross(r34, r12), r13);
        g = (sgn <= 0.0f) ? -g : g;

        acc[c_seg_p[i2]] += g;   // compile-time index after unroll
    }

    __syncthreads();   // everyone done reading j1 before aliasing it as red

    float* red = smem;                 // [FPB][16][5]
#pragma unroll
    for (int p = 0; p < 5; ++p)
        red[(k * 16 + i1) * 5 + p] = acc[p] * 0.07957747154594767f;  // 1/(4*pi)
    __syncthreads();

    // 400 items = FPB frames x 25 bins; grouped sum over i1 in path(p1).
    for (int item = t; item < FPB * 25; item += 256) {
        int kk  = item / 25;
        int bin = item - kk * 25;
        int p1 = bin / 5, p2 = bin - p1 * 5;
        float s = 0.0f;
        for (int i = c_grp_s[p1]; i < c_grp_e[p1]; ++i)
            s += red[(kk * 16 + i) * 5 + p2];
        gli[((size_t)b * NF + f0 + kk) * 25 + bin] = s;
    }
}

// out[b,f] = max_p |gli[b,f+1,p] - gli[b,f,p]|
__global__ __launch_bounds__(256)
void vel_kernel(const float* __restrict__ gli, float* __restrict__ out)
{
    const int f = blockIdx.x * blockDim.x + threadIdx.x;
    const int b = blockIdx.y;
    if (f >= NF - 1) return;

    const float* p0 = gli + ((size_t)b * NF + f) * 25;
    float m = 0.0f;
#pragma unroll
    for (int p = 0; p < 25; ++p)
        m = fmaxf(m, fabsf(p0[p + 25] - p0[p]));
    out[(size_t)b * (NF - 1) + f] = m;
}

extern "C" void kernel_launch(void* const* d_in, const int* in_sizes, int n_in,
                              void* d_out, int out_size, void* d_ws, size_t ws_size,
                              hipStream_t stream)
{
    const float* m1 = (const float*)d_in[0];
    const float* m2 = (const float*)d_in[1];
    float* out = (float*)d_out;
    float* gli = (float*)d_ws;   // 32*1024*25*4 = 3.3 MB

    hipLaunchKernelGGL(gli_kernel, dim3(NF / FPB, NB), dim3(256), 0, stream,
                       m1, m2, gli);
    hipLaunchKernelGGL(vel_kernel, dim3((NF - 1 + 255) / 256, NB), dim3(256),
                       0, stream, gli, out);
}

// Round 5
// 92.840 us; speedup vs baseline: 1.4414x; 1.0783x over previous
//
#include <hip/hip_runtime.h>
#include <hip/hip_bf16.h>

// Gauss linking integral between kinematic-chain segment pairs.
// motion1, motion2: (B=32, F=1024, J=22, 3) fp32.
// R4: two frames per thread as float2 -> packed fp32 (v_pk_*) for all
// subs/crosses/dots/poly-FMAs; constexpr tables so unrolled acc index folds.
// Thread = (frame-pair kp, i1). Block = 256 thr = 16 kp x 16 i1 = 32 frames.

#define NF 1024
#define NB 32
#define FPB 32              // frames per block (16 float2 pairs)

typedef float v2f __attribute__((ext_vector_type(2)));

struct W3 { v2f x, y, z; };

__device__ __forceinline__ v2f FMA2(v2f a, v2f b, v2f c) {
    return __builtin_elementwise_fma(a, b, c);
}
__device__ __forceinline__ W3 wsub(W3 a, W3 b) { return {a.x-b.x, a.y-b.y, a.z-b.z}; }
__device__ __forceinline__ W3 wcross(W3 a, W3 b) {
    return { FMA2(a.y, b.z, -(a.z*b.y)),
             FMA2(a.z, b.x, -(a.x*b.z)),
             FMA2(a.x, b.y, -(a.y*b.x)) };
}
__device__ __forceinline__ v2f wdot(W3 a, W3 b) {
    return FMA2(a.x, b.x, FMA2(a.y, b.y, a.z*b.z));
}
__device__ __forceinline__ v2f rsq_guard(v2f q) {
    v2f r;
    r.x = (q.x > 0.0f) ? __builtin_amdgcn_rsqf(q.x) : 0.0f;
    r.y = (q.y > 0.0f) ? __builtin_amdgcn_rsqf(q.y) : 0.0f;
    return r;
}
__device__ __forceinline__ v2f clamp2(v2f v) {
    const float lo = -1.0f + 1e-7f, hi = 1.0f - 1e-7f;
    v.x = fminf(fmaxf(v.x, lo), hi);
    v.y = fminf(fmaxf(v.y, lo), hi);
    return v;
}
// asin via Abramowitz-Stegun 4.4.46 (7-term), packed polynomial.
__device__ __forceinline__ v2f asin2(v2f x) {
    v2f ax; ax.x = fabsf(x.x); ax.y = fabsf(x.y);
    v2f p = FMA2(ax, (v2f)(-0.0012624911f), (v2f)(0.0066700901f));
    p = FMA2(ax, p, (v2f)(-0.0170881256f));
    p = FMA2(ax, p, (v2f)( 0.0308918810f));
    p = FMA2(ax, p, (v2f)(-0.0501743046f));
    p = FMA2(ax, p, (v2f)( 0.0889789874f));
    p = FMA2(ax, p, (v2f)(-0.2145988016f));
    p = FMA2(ax, p, (v2f)( 1.5707963050f));
    v2f om = (v2f)(1.0f) - ax;
    v2f s; s.x = __builtin_amdgcn_sqrtf(om.x); s.y = __builtin_amdgcn_sqrtf(om.y);
    v2f r = FMA2(-s, p, (v2f)(1.57079632679f));
    r.x = copysignf(r.x, x.x);
    r.y = copysignf(r.y, x.y);
    return r;
}

#define JSTRIDE 34   // pad 66x[FPB] rows to 34 floats: b64-aligned, spread banks

__global__ __launch_bounds__(256)
void gli_kernel(const float* __restrict__ m1, const float* __restrict__ m2,
                float* __restrict__ gli)
{
    __shared__ float smem[66 * JSTRIDE * 2];   // jT1 | jT2, transposed [66][34]
    float* jT1 = smem;
    float* jT2 = smem + 66 * JSTRIDE;

    const int f0 = blockIdx.x * FPB;
    const int b  = blockIdx.y;
    const int t  = threadIdx.x;

    // Stage FPB frames transposed: jT[off][f] = m[f][off]. Coalesced global.
    const size_t mbase = ((size_t)b * NF + f0) * 66;
    for (int i = t; i < FPB * 66; i += 256) {
        int f   = i / 66;
        int off = i - f * 66;
        jT1[off * JSTRIDE + f] = m1[mbase + i];
        jT2[off * JSTRIDE + f] = m2[mbase + i];
    }
    __syncthreads();

    constexpr int seg_a[16] = {2,5,8,  1,4,7,  3,6,9,12,  14,17,19,  13,16,18};
    constexpr int seg_b[16] = {5,8,11, 4,7,10, 6,9,12,15, 17,19,21,  16,18,20};
    constexpr int seg_p[16] = {0,0,0,  1,1,1,  2,2,2,2,   3,3,3,     4,4,4};

    const int kp = t >> 4;    // frame pair: frames 2kp, 2kp+1
    const int i1 = t & 15;    // motion1 segment (p1 fixed per thread)
    const int fc = 2 * kp;

    const int a1 = seg_a[i1] * 3, b1 = seg_b[i1] * 3;

    #define LD2(base, off) (*(const v2f*)&(base)[(off) * JSTRIDE + fc])
    W3 S1{LD2(jT1, a1), LD2(jT1, a1+1), LD2(jT1, a1+2)};
    W3 E1{LD2(jT1, b1), LD2(jT1, b1+1), LD2(jT1, b1+2)};
    W3 r12 = wsub(E1, S1);

    v2f acc[5] = {(v2f)(0.0f), (v2f)(0.0f), (v2f)(0.0f), (v2f)(0.0f), (v2f)(0.0f)};

#pragma unroll
    for (int i2 = 0; i2 < 16; ++i2) {
        const int a2 = seg_a[i2] * 3, b2 = seg_b[i2] * 3;
        W3 S2{LD2(jT2, a2), LD2(jT2, a2+1), LD2(jT2, a2+2)};
        W3 E2{LD2(jT2, b2), LD2(jT2, b2+1), LD2(jT2, b2+2)};

        W3 r13 = wsub(S2, S1);
        W3 r14 = wsub(E2, S1);
        W3 r23 = wsub(S2, E1);
        W3 r24 = wsub(E2, E1);
        W3 r34 = wsub(E2, S2);

        W3 c0 = wcross(r13, r14);
        W3 c1 = wcross(r14, r24);
        W3 c2 = wcross(r24, r23);
        W3 c3 = wcross(r23, r13);

        v2f n0 = wdot(c0, c0), n1 = wdot(c1, c1);
        v2f n2 = wdot(c2, c2), n3 = wdot(c3, c3);

        v2f i01 = rsq_guard(n0 * n1);
        v2f i12 = rsq_guard(n1 * n2);
        v2f i23 = rsq_guard(n2 * n3);
        v2f i30 = rsq_guard(n3 * n0);

        v2f d0 = clamp2(wdot(c0, c1) * i01);
        v2f d1 = clamp2(wdot(c1, c2) * i12);
        v2f d2 = clamp2(wdot(c2, c3) * i23);
        v2f d3 = clamp2(wdot(c3, c0) * i30);

        v2f g = asin2(d0) + asin2(d1) + asin2(d2) + asin2(d3);

        v2f sgn = wdot(wcross(r34, r12), r13);
        g.x = (sgn.x <= 0.0f) ? -g.x : g.x;
        g.y = (sgn.y <= 0.0f) ? -g.y : g.y;

        acc[seg_p[i2]] += g;   // constexpr index -> registers, no scratch
    }
    #undef LD2

    __syncthreads();   // staging dead; alias smem as red[FPB][81]

    float* red = smem;   // red[f * 81 + i1*5 + p], 32*81 = 2592 floats
#pragma unroll
    for (int p = 0; p < 5; ++p) {
        red[(fc    ) * 81 + i1 * 5 + p] = acc[p].x * 0.07957747154594767f;
        red[(fc + 1) * 81 + i1 * 5 + p] = acc[p].y * 0.07957747154594767f;
    }
    __syncthreads();

    // 800 items = 32 frames x 25 bins; grouped sum over i1 in path(p1).
    constexpr int grp_s[5] = {0, 3, 6, 10, 13};
    constexpr int grp_e[5] = {3, 6, 10, 13, 16};
    for (int item = t; item < FPB * 25; item += 256) {
        int f   = item / 25;
        int bin = item - f * 25;
        int p1 = bin / 5, p2 = bin - p1 * 5;
        float s = 0.0f;
        for (int i = grp_s[p1]; i < grp_e[p1]; ++i)
            s += red[f * 81 + i * 5 + p2];
        gli[((size_t)b * NF + f0 + f) * 25 + bin] = s;
    }
}

// out[b,f] = max_p |gli[b,f+1,p] - gli[b,f,p]|
__global__ __launch_bounds__(256)
void vel_kernel(const float* __restrict__ gli, float* __restrict__ out)
{
    const int f = blockIdx.x * blockDim.x + threadIdx.x;
    const int b = blockIdx.y;
    if (f >= NF - 1) return;

    const float* p0 = gli + ((size_t)b * NF + f) * 25;
    float m = 0.0f;
#pragma unroll
    for (int p = 0; p < 25; ++p)
        m = fmaxf(m, fabsf(p0[p + 25] - p0[p]));
    out[(size_t)b * (NF - 1) + f] = m;
}

extern "C" void kernel_launch(void* const* d_in, const int* in_sizes, int n_in,
                              void* d_out, int out_size, void* d_ws, size_t ws_size,
                              hipStream_t stream)
{
    const float* m1 = (const float*)d_in[0];
    const float* m2 = (const float*)d_in[1];
    float* out = (float*)d_out;
    float* gli = (float*)d_ws;   // 32*1024*25*4 = 3.3 MB

    hipLaunchKernelGGL(gli_kernel, dim3(NF / FPB, NB), dim3(256), 0, stream,
                       m1, m2, gli);
    hipLaunchKernelGGL(vel_kernel, dim3((NF - 1 + 255) / 256, NB), dim3(256),
                       0, stream, gli, out);
}

// Round 6
// 91.703 us; speedup vs baseline: 1.4592x; 1.0124x over previous
//
#include <hip/hip_runtime.h>
#include <hip/hip_bf16.h>

// Gauss linking integral between kinematic-chain segment pairs.
// motion1, motion2: (B=32, F=1024, J=22, 3) fp32.
// R5: packed float2 math (2 frames/thread) AND full occupancy: the 16-i2 loop
// is split across 2 thread-halves (8 packed iters each, compile-time bounds).
// Block = 256 thr = 8 frame-pairs x 16 i1 x 2 halves -> 16 frames/block,
// grid = 64x32 = 2048 blocks = 8 blocks/CU = 32 waves/CU (HW cap).

#define NF 1024
#define NB 32
#define FPB 16              // frames per block (8 float2 pairs)
#define JSTRIDE 18          // 16 frames + 2 pad: even (b64-aligned float2)

typedef float v2f __attribute__((ext_vector_type(2)));

struct W3 { v2f x, y, z; };

__device__ __forceinline__ v2f FMA2(v2f a, v2f b, v2f c) {
    return __builtin_elementwise_fma(a, b, c);
}
__device__ __forceinline__ W3 wsub(W3 a, W3 b) { return {a.x-b.x, a.y-b.y, a.z-b.z}; }
__device__ __forceinline__ W3 wcross(W3 a, W3 b) {
    return { FMA2(a.y, b.z, -(a.z*b.y)),
             FMA2(a.z, b.x, -(a.x*b.z)),
             FMA2(a.x, b.y, -(a.y*b.x)) };
}
__device__ __forceinline__ v2f wdot(W3 a, W3 b) {
    return FMA2(a.x, b.x, FMA2(a.y, b.y, a.z*b.z));
}
__device__ __forceinline__ v2f rsq_guard(v2f q) {
    v2f r;
    r.x = (q.x > 0.0f) ? __builtin_amdgcn_rsqf(q.x) : 0.0f;
    r.y = (q.y > 0.0f) ? __builtin_amdgcn_rsqf(q.y) : 0.0f;
    return r;
}
__device__ __forceinline__ v2f clamp2(v2f v) {
    const float lo = -1.0f + 1e-7f, hi = 1.0f - 1e-7f;
    v.x = fminf(fmaxf(v.x, lo), hi);
    v.y = fminf(fmaxf(v.y, lo), hi);
    return v;
}
// asin via Abramowitz-Stegun 4.4.46 (7-term), packed polynomial.
__device__ __forceinline__ v2f asin2(v2f x) {
    v2f ax; ax.x = fabsf(x.x); ax.y = fabsf(x.y);
    v2f p = FMA2(ax, (v2f)(-0.0012624911f), (v2f)(0.0066700901f));
    p = FMA2(ax, p, (v2f)(-0.0170881256f));
    p = FMA2(ax, p, (v2f)( 0.0308918810f));
    p = FMA2(ax, p, (v2f)(-0.0501743046f));
    p = FMA2(ax, p, (v2f)( 0.0889789874f));
    p = FMA2(ax, p, (v2f)(-0.2145988016f));
    p = FMA2(ax, p, (v2f)( 1.5707963050f));
    v2f om = (v2f)(1.0f) - ax;
    v2f s; s.x = __builtin_amdgcn_sqrtf(om.x); s.y = __builtin_amdgcn_sqrtf(om.y);
    v2f r = FMA2(-s, p, (v2f)(1.57079632679f));
    r.x = copysignf(r.x, x.x);
    r.y = copysignf(r.y, x.y);
    return r;
}

__global__ __launch_bounds__(256)
void gli_kernel(const float* __restrict__ m1, const float* __restrict__ m2,
                float* __restrict__ gli)
{
    // union: staging jT1|jT2 (2*66*18 = 2376 floats) vs red (2*16*16*5 = 2560)
    __shared__ float smem[2 * FPB * 16 * 5];
    float* jT1 = smem;
    float* jT2 = smem + 66 * JSTRIDE;

    const int f0 = blockIdx.x * FPB;
    const int b  = blockIdx.y;
    const int t  = threadIdx.x;

    // Stage FPB frames transposed: jT[off][f] = m[f][off]. Coalesced global.
    const size_t mbase = ((size_t)b * NF + f0) * 66;
    for (int i = t; i < FPB * 66; i += 256) {
        int f   = i / 66;
        int off = i - f * 66;
        jT1[off * JSTRIDE + f] = m1[mbase + i];
        jT2[off * JSTRIDE + f] = m2[mbase + i];
    }
    __syncthreads();

    constexpr int seg_a[16] = {2,5,8,  1,4,7,  3,6,9,12,  14,17,19,  13,16,18};
    constexpr int seg_b[16] = {5,8,11, 4,7,10, 6,9,12,15, 17,19,21,  16,18,20};
    constexpr int seg_p[16] = {0,0,0,  1,1,1,  2,2,2,2,   3,3,3,     4,4,4};

    const int half = t >> 7;         // which 8 i2's this thread owns
    const int kp   = (t >> 4) & 7;   // frame pair: frames 2kp, 2kp+1
    const int i1   = t & 15;         // motion1 segment (p1 fixed per thread)
    const int fc   = 2 * kp;

    const int a1 = seg_a[i1] * 3, b1 = seg_b[i1] * 3;

    #define LD2(base, off) (*(const v2f*)&(base)[(off) * JSTRIDE + fc])
    W3 S1{LD2(jT1, a1), LD2(jT1, a1+1), LD2(jT1, a1+2)};
    W3 E1{LD2(jT1, b1), LD2(jT1, b1+1), LD2(jT1, b1+2)};
    W3 r12 = wsub(E1, S1);

    v2f acc[5] = {(v2f)(0.0f), (v2f)(0.0f), (v2f)(0.0f), (v2f)(0.0f), (v2f)(0.0f)};

    auto body = [&](int i2) {
        const int a2 = seg_a[i2] * 3, b2 = seg_b[i2] * 3;
        W3 S2{LD2(jT2, a2), LD2(jT2, a2+1), LD2(jT2, a2+2)};
        W3 E2{LD2(jT2, b2), LD2(jT2, b2+1), LD2(jT2, b2+2)};

        W3 r13 = wsub(S2, S1);
        W3 r14 = wsub(E2, S1);
        W3 r23 = wsub(S2, E1);
        W3 r24 = wsub(E2, E1);
        W3 r34 = wsub(E2, S2);

        W3 c0 = wcross(r13, r14);
        W3 c1 = wcross(r14, r24);
        W3 c2 = wcross(r24, r23);
        W3 c3 = wcross(r23, r13);

        v2f n0 = wdot(c0, c0), n1 = wdot(c1, c1);
        v2f n2 = wdot(c2, c2), n3 = wdot(c3, c3);

        v2f i01 = rsq_guard(n0 * n1);
        v2f i12 = rsq_guard(n1 * n2);
        v2f i23 = rsq_guard(n2 * n3);
        v2f i30 = rsq_guard(n3 * n0);

        v2f d0 = clamp2(wdot(c0, c1) * i01);
        v2f d1 = clamp2(wdot(c1, c2) * i12);
        v2f d2 = clamp2(wdot(c2, c3) * i23);
        v2f d3 = clamp2(wdot(c3, c0) * i30);

        v2f g = asin2(d0) + asin2(d1) + asin2(d2) + asin2(d3);

        v2f sgn = wdot(wcross(r34, r12), r13);
        g.x = (sgn.x <= 0.0f) ? -g.x : g.x;
        g.y = (sgn.y <= 0.0f) ? -g.y : g.y;

        acc[seg_p[i2]] += g;   // i2 compile-time after unroll -> folds
    };

    if (half == 0) {           // wave-uniform branch (t>>7)
#pragma unroll
        for (int i2 = 0; i2 < 8; ++i2) body(i2);
    } else {
#pragma unroll
        for (int i2 = 8; i2 < 16; ++i2) body(i2);
    }
    #undef LD2

    __syncthreads();   // staging dead; alias smem as red[2][FPB][16][5]

    float* red = smem;
#pragma unroll
    for (int p = 0; p < 5; ++p) {
        red[(((half * FPB) + fc    ) * 16 + i1) * 5 + p] = acc[p].x * 0.07957747154594767f;
        red[(((half * FPB) + fc + 1) * 16 + i1) * 5 + p] = acc[p].y * 0.07957747154594767f;
    }
    __syncthreads();

    // 400 items = FPB frames x 25 bins; sum halves and i1 in path(p1).
    constexpr int grp_s[5] = {0, 3, 6, 10, 13};
    constexpr int grp_e[5] = {3, 6, 10, 13, 16};
    for (int item = t; item < FPB * 25; item += 256) {
        int f   = item / 25;
        int bin = item - f * 25;
        int p1 = bin / 5, p2 = bin - p1 * 5;
        float s = 0.0f;
        for (int i = grp_s[p1]; i < grp_e[p1]; ++i)
            s += red[((f          ) * 16 + i) * 5 + p2]
               + red[((f + FPB    ) * 16 + i) * 5 + p2];
        gli[((size_t)b * NF + f0 + f) * 25 + bin] = s;
    }
}

// out[b,f] = max_p |gli[b,f+1,p] - gli[b,f,p]|
__global__ __launch_bounds__(256)
void vel_kernel(const float* __restrict__ gli, float* __restrict__ out)
{
    const int f = blockIdx.x * blockDim.x + threadIdx.x;
    const int b = blockIdx.y;
    if (f >= NF - 1) return;

    const float* p0 = gli + ((size_t)b * NF + f) * 25;
    float m = 0.0f;
#pragma unroll
    for (int p = 0; p < 25; ++p)
        m = fmaxf(m, fabsf(p0[p + 25] - p0[p]));
    out[(size_t)b * (NF - 1) + f] = m;
}

extern "C" void kernel_launch(void* const* d_in, const int* in_sizes, int n_in,
                              void* d_out, int out_size, void* d_ws, size_t ws_size,
                              hipStream_t stream)
{
    const float* m1 = (const float*)d_in[0];
    const float* m2 = (const float*)d_in[1];
    float* out = (float*)d_out;
    float* gli = (float*)d_ws;   // 32*1024*25*4 = 3.3 MB

    hipLaunchKernelGGL(gli_kernel, dim3(NF / FPB, NB), dim3(256), 0, stream,
                       m1, m2, gli);
    hipLaunchKernelGGL(vel_kernel, dim3((NF - 1 + 255) / 256, NB), dim3(256),
                       0, stream, gli, out);
}